// Round 1
// 457.966 us; speedup vs baseline: 1.1993x; 1.1993x over previous
//
#include <hip/hip_runtime.h>
#include <stdint.h>

// B=8, C=256, H=128, W=128. out = W[256,1280] @ concat(x,cummaxH,revcummaxH,cummaxW,revcummaxW) + bias
// GEMM: M=256, K=1280, N=131072 bf16 MFMA.
// ws: wsA [kb=160][m=256][j=8] bf16 weights (granule layout, k=kb*8+j);
//     wsB [kb=160][n=131072][j=8] bf16.

#define N_  131072
#define K_  1280

typedef unsigned short ushort8v __attribute__((ext_vector_type(8)));
typedef unsigned short ushort4v __attribute__((ext_vector_type(4)));
typedef short          short8v  __attribute__((ext_vector_type(8)));
typedef float          float4v  __attribute__((ext_vector_type(4)));

__device__ __forceinline__ unsigned short f2bf(float f) {
    unsigned int u = __builtin_bit_cast(unsigned int, f);
    u += 0x7fffu + ((u >> 16) & 1u);           // RNE
    return (unsigned short)(u >> 16);
}

__device__ __forceinline__ void load_lds16(const void* g, void* l) {
    __builtin_amdgcn_global_load_lds(
        (const __attribute__((address_space(1))) uint32_t*)g,
        (__attribute__((address_space(3))) uint32_t*)l,
        16, 0, 0);
}

// ---- weights fp32 -> bf16, granule layout wsA[kb][m][8] ----
__global__ void repack_w(const float* __restrict__ w, unsigned short* __restrict__ wsA) {
    int idx = blockIdx.x * 256 + threadIdx.x;   // 0..81919, 4 k-elements each
    float4 v = ((const float4*)w)[idx];
    int m = idx / 320;                          // w is [256][1280] row-major
    int k = (idx - m * 320) << 2;
    ushort4v o = { f2bf(v.x), f2bf(v.y), f2bf(v.z), f2bf(v.w) };
    *(ushort4v*)(wsA + ((size_t)(k >> 3) << 11) + (m << 3) + (k & 7)) = o;
}

// ---- v0 (x), v1 (prefix max over h), v2 (suffix max over h) ----
// grid 1024 = (b:8, cb:32, wq:4); block 256 = (j:8 major, wi:32).
__global__ __launch_bounds__(256) void scan_h(const float* __restrict__ x,
                                              unsigned short* __restrict__ wsB) {
    int idx = blockIdx.x;
    int wq = idx & 3, cb = (idx >> 2) & 31, b = idx >> 7;
    int t = threadIdx.x;
    int j = t >> 5, wi = t & 31;
    const float* src = x + (((size_t)(b * 256 + cb * 8 + j)) << 14) + wq * 32 + wi;
    unsigned short* d0 = wsB + (((size_t)(cb)      * N_) << 3);
    unsigned short* d1 = wsB + (((size_t)(32 + cb) * N_) << 3);
    unsigned short* d2 = wsB + (((size_t)(64 + cb) * N_) << 3);
    size_t nbase = ((size_t)b << 14) + wq * 32;

    __shared__ unsigned short sm0[16 * 32 * 8];   // [hh][wi][j], 8 KB
    __shared__ unsigned short sm1[16 * 32 * 8];

    float r = -INFINITY;
    for (int hb = 0; hb < 8; ++hb) {
        int h0 = hb << 4;
#pragma unroll
        for (int hh = 0; hh < 16; ++hh) {
            float v = src[(size_t)(h0 + hh) << 7];
            r = fmaxf(r, v);
            sm0[((hh << 5) + wi) * 8 + j] = f2bf(v);
            sm1[((hh << 5) + wi) * 8 + j] = f2bf(r);
        }
        __syncthreads();
#pragma unroll
        for (int k = 0; k < 2; ++k) {
            int p = t + (k << 8);
            int hh = p >> 5, wo = p & 31;
            size_t n = nbase + (size_t)(h0 + hh) * 128 + wo;
            ushort8v a = *(const ushort8v*)(sm0 + (((hh << 5) + wo) << 3));
            ushort8v c = *(const ushort8v*)(sm1 + (((hh << 5) + wo) << 3));
            *(ushort8v*)(d0 + (n << 3)) = a;
            *(ushort8v*)(d1 + (n << 3)) = c;
        }
        __syncthreads();
    }
    // suffix pass (reads x again; block footprint is L3-resident)
    r = -INFINITY;
    for (int hb = 7; hb >= 0; --hb) {
        int h0 = hb << 4;
#pragma unroll
        for (int hh = 15; hh >= 0; --hh) {
            float v = src[(size_t)(h0 + hh) << 7];
            r = fmaxf(r, v);
            sm0[((hh << 5) + wi) * 8 + j] = f2bf(r);
        }
        __syncthreads();
#pragma unroll
        for (int k = 0; k < 2; ++k) {
            int p = t + (k << 8);
            int hh = p >> 5, wo = p & 31;
            size_t n = nbase + (size_t)(h0 + hh) * 128 + wo;
            *(ushort8v*)(d2 + (n << 3)) = *(const ushort8v*)(sm0 + (((hh << 5) + wo) << 3));
        }
        __syncthreads();
    }
}

// ---- v3 (prefix max over w), v4 (suffix max over w) ----
__global__ __launch_bounds__(256) void scan_w(const float* __restrict__ x,
                                              unsigned short* __restrict__ wsB) {
    int idx = blockIdx.x;
    int hq = idx & 3, cb = (idx >> 2) & 31, b = idx >> 7;
    int t = threadIdx.x;
    int j = t >> 5, hh = t & 31;
    (void)j; (void)hh;

    __shared__ float xs[16][260];                 // [w][row], row = c8*32+hr, pad 260
    __shared__ unsigned short po[32][136];        // [hh][w*8+j], row-pad 136

    const float* xb = x + (((size_t)(b * 256 + cb * 8)) << 14) + ((size_t)(hq * 32) << 7);
    unsigned short* d3 = wsB + (((size_t)(96  + cb) * N_) << 3);
    unsigned short* d4 = wsB + (((size_t)(128 + cb) * N_) << 3);
    size_t nrow0 = ((size_t)b << 14) + (size_t)(hq * 32) * 128;

    // forward sweep: prefix -> d3
    {
        float r = -INFINITY;
        for (int wc = 0; wc < 8; ++wc) {
#pragma unroll
            for (int k = 0; k < 4; ++k) {
                int f = t + (k << 8);
                int row = f >> 2, pos = f & 3;
                float4 v = *(const float4*)(xb + ((size_t)(row >> 5) << 14) +
                                            ((row & 31) << 7) + (wc << 4) + (pos << 2));
                xs[pos * 4 + 0][row] = v.x; xs[pos * 4 + 1][row] = v.y;
                xs[pos * 4 + 2][row] = v.z; xs[pos * 4 + 3][row] = v.w;
            }
            __syncthreads();
#pragma unroll
            for (int w = 0; w < 16; ++w) {
                r = fmaxf(r, xs[w][t]);
                po[t & 31][w * 8 + (t >> 5)] = f2bf(r);
            }
            __syncthreads();
#pragma unroll
            for (int k = 0; k < 2; ++k) {
                int p = t + (k << 8);
                int ph = p >> 4, pw = p & 15;
                size_t n = nrow0 + (size_t)ph * 128 + (wc << 4) + pw;
                *(ushort8v*)(d3 + (n << 3)) = *(const ushort8v*)(&po[ph][pw << 3]);
            }
            __syncthreads();
        }
    }
    // backward sweep: suffix -> d4
    {
        float r = -INFINITY;
        for (int wc = 7; wc >= 0; --wc) {
#pragma unroll
            for (int k = 0; k < 4; ++k) {
                int f = t + (k << 8);
                int row = f >> 2, pos = f & 3;
                float4 v = *(const float4*)(xb + ((size_t)(row >> 5) << 14) +
                                            ((row & 31) << 7) + (wc << 4) + (pos << 2));
                xs[pos * 4 + 0][row] = v.x; xs[pos * 4 + 1][row] = v.y;
                xs[pos * 4 + 2][row] = v.z; xs[pos * 4 + 3][row] = v.w;
            }
            __syncthreads();
#pragma unroll
            for (int w = 15; w >= 0; --w) {
                r = fmaxf(r, xs[w][t]);
                po[t & 31][w * 8 + (t >> 5)] = f2bf(r);
            }
            __syncthreads();
#pragma unroll
            for (int k = 0; k < 2; ++k) {
                int p = t + (k << 8);
                int ph = p >> 4, pw = p & 15;
                size_t n = nrow0 + (size_t)ph * 128 + (wc << 4) + pw;
                *(ushort8v*)(d4 + (n << 3)) = *(const ushort8v*)(&po[ph][pw << 3]);
            }
            __syncthreads();
        }
    }
}

// ---- GEMM: C[256,131072] = A[256,1280] * B[1280,131072], bf16 MFMA ----
// 256x256 tile, BK=64, 8 waves (2M x 4N), double-buffered 128 KiB LDS,
// stage-ahead 1 tile with counted vmcnt(8), raw s_barrier (no vmcnt(0) drain in loop).

__device__ __forceinline__ void stage_tile(
    const unsigned short* __restrict__ wsA, const unsigned short* __restrict__ wsB,
    int t, int n0, unsigned short* As, unsigned short* Bs, int tid) {
    // A-tile: 2048 granules of 16 B, contiguous in wsA (kb-major) -> linear LDS
    const unsigned short* ga = wsA + ((((size_t)t << 11) + tid) << 3);
#pragma unroll
    for (int r = 0; r < 4; ++r)
        load_lds16(ga + (r << 12), As + (((r << 9) + tid) << 3));
    // B-tile: kb in [8t, 8t+8), n in [n0, n0+256)
    int kb0 = t << 3;
#pragma unroll
    for (int r = 0; r < 4; ++r) {
        int idx = (r << 9) + tid;
        load_lds16(wsB + (((size_t)(kb0 + (idx >> 8)) * N_ + n0 + (idx & 255)) << 3),
                   Bs + ((size_t)idx << 3));
    }
}

__device__ __forceinline__ void compute_tile(
    const unsigned short* __restrict__ Ab, const unsigned short* __restrict__ Bb,
    int wr, int wc, int q, int lr, float4v (&acc)[8][4]) {
#pragma unroll
    for (int h = 0; h < 2; ++h) {
        short8v a[8], bb[4];
        int kq = (h << 2) + q;
#pragma unroll
        for (int mi = 0; mi < 8; ++mi)
            a[mi] = *(const short8v*)(Ab + (((kq << 8) + (wr << 7) + (mi << 4) + lr) << 3));
#pragma unroll
        for (int ni = 0; ni < 4; ++ni)
            bb[ni] = *(const short8v*)(Bb + (((kq << 8) + (wc << 6) + (ni << 4) + lr) << 3));
        __builtin_amdgcn_s_setprio(1);
#pragma unroll
        for (int mi = 0; mi < 8; ++mi)
#pragma unroll
            for (int ni = 0; ni < 4; ++ni)
                acc[mi][ni] = __builtin_amdgcn_mfma_f32_16x16x32_bf16(a[mi], bb[ni], acc[mi][ni], 0, 0, 0);
        __builtin_amdgcn_s_setprio(0);
    }
}

__global__ __launch_bounds__(512, 2) void gemm_k(
    const unsigned short* __restrict__ wsA, const unsigned short* __restrict__ wsB,
    const float* __restrict__ bias, float* __restrict__ out) {
    __shared__ __align__(16) unsigned short As[2][16384];   // 2 x 32 KB
    __shared__ __align__(16) unsigned short Bs[2][16384];   // 2 x 32 KB

    int tid  = threadIdx.x;
    int lane = tid & 63, wid = tid >> 6;
    int wr = wid >> 2, wc = wid & 3;          // wave tile: 128(M) x 64(N)
    int q  = lane >> 4, lr = lane & 15;
    int bid = blockIdx.x;
    int n0 = (((bid & 7) << 6) + (bid >> 3)) << 8;   // XCD-aware swizzle, 512 % 8 == 0

    float4v acc[8][4];
#pragma unroll
    for (int mi = 0; mi < 8; ++mi)
#pragma unroll
        for (int ni = 0; ni < 4; ++ni)
            acc[mi][ni] = (float4v){0.f, 0.f, 0.f, 0.f};

    // prologue: tiles 0 and 1 in flight
    stage_tile(wsA, wsB, 0, n0, As[0], Bs[0], tid);
    stage_tile(wsA, wsB, 1, n0, As[1], Bs[1], tid);
    asm volatile("s_waitcnt vmcnt(8)" ::: "memory");   // tile 0 landed, tile 1 outstanding
    __builtin_amdgcn_s_barrier();
    __builtin_amdgcn_sched_barrier(0);

#pragma unroll 1
    for (int t = 0; t < 18; t += 2) {
        // tile t from buf0; stage t+2 into buf0 after all reads done
        compute_tile(As[0], Bs[0], wr, wc, q, lr, acc);
        __builtin_amdgcn_s_barrier();                  // buf0 reads complete block-wide
        __builtin_amdgcn_sched_barrier(0);
        stage_tile(wsA, wsB, t + 2, n0, As[0], Bs[0], tid);
        __builtin_amdgcn_sched_barrier(0);
        asm volatile("s_waitcnt vmcnt(8)" ::: "memory");   // tile t+1 landed; t+2 in flight
        __builtin_amdgcn_s_barrier();
        __builtin_amdgcn_sched_barrier(0);

        // tile t+1 from buf1; stage t+3 into buf1
        compute_tile(As[1], Bs[1], wr, wc, q, lr, acc);
        __builtin_amdgcn_s_barrier();
        __builtin_amdgcn_sched_barrier(0);
        stage_tile(wsA, wsB, t + 3, n0, As[1], Bs[1], tid);
        __builtin_amdgcn_sched_barrier(0);
        asm volatile("s_waitcnt vmcnt(8)" ::: "memory");   // tile t+2 landed; t+3 in flight
        __builtin_amdgcn_s_barrier();
        __builtin_amdgcn_sched_barrier(0);
    }
    // tail: tiles 18 (buf0) and 19 (buf1), no more staging
    compute_tile(As[0], Bs[0], wr, wc, q, lr, acc);
    __builtin_amdgcn_s_barrier();
    asm volatile("s_waitcnt vmcnt(0)" ::: "memory");       // tile 19 landed
    __builtin_amdgcn_s_barrier();
    __builtin_amdgcn_sched_barrier(0);
    compute_tile(As[1], Bs[1], wr, wc, q, lr, acc);

    // epilogue: rows = wr*128 + mi*16 + q*4 + r; cols = n0 + wc*64 + ni*16 + lr
#pragma unroll
    for (int mi = 0; mi < 8; ++mi) {
        int rowb = (wr << 7) + (mi << 4) + (q << 2);
#pragma unroll
        for (int ni = 0; ni < 4; ++ni) {
            int col = n0 + (wc << 6) + (ni << 4) + lr;
            int b   = col >> 14, p = col & 16383;
            float* op = out + ((size_t)((b << 8) + rowb) << 14) + p;
#pragma unroll
            for (int r = 0; r < 4; ++r)
                op[(size_t)r << 14] = acc[mi][ni][r] + bias[rowb + r];
        }
    }
}

extern "C" void kernel_launch(void* const* d_in, const int* in_sizes, int n_in,
                              void* d_out, int out_size, void* d_ws, size_t ws_size,
                              hipStream_t stream) {
    const float* x  = (const float*)d_in[0];
    const float* cw = (const float*)d_in[1];
    const float* cb = (const float*)d_in[2];
    float* out = (float*)d_out;

    unsigned short* wsA = (unsigned short*)d_ws;
    unsigned short* wsB = wsA + 327680;

    repack_w<<<320, 256, 0, stream>>>(cw, wsA);
    scan_h<<<1024, 256, 0, stream>>>(x, wsB);
    scan_w<<<1024, 256, 0, stream>>>(x, wsB);
    gemm_k<<<512, 512, 0, stream>>>(wsA, wsB, cb, out);
}

// Round 3
// 439.458 us; speedup vs baseline: 1.2498x; 1.0421x over previous
//
#include <hip/hip_runtime.h>
#include <stdint.h>

// B=8, C=256, H=128, W=128. out = W[256,1280] @ concat(x,cummaxH,revcummaxH,cummaxW,revcummaxW) + bias
// GEMM: M=256, K=1280, N=131072 bf16 MFMA.
// ws: wsA [kb=160][m=256][j=8] bf16 weights (granule layout, k=kb*8+j);
//     wsB [kb=160][n=131072][j=8] bf16.

#define N_  131072
#define K_  1280

typedef unsigned short ushort8v __attribute__((ext_vector_type(8)));
typedef unsigned short ushort4v __attribute__((ext_vector_type(4)));
typedef short          short8v  __attribute__((ext_vector_type(8)));
typedef float          float4v  __attribute__((ext_vector_type(4)));

__device__ __forceinline__ unsigned short f2bf(float f) {
    unsigned int u = __builtin_bit_cast(unsigned int, f);
    u += 0x7fffu + ((u >> 16) & 1u);           // RNE
    return (unsigned short)(u >> 16);
}

__device__ __forceinline__ void load_lds16(const void* g, void* l) {
    __builtin_amdgcn_global_load_lds(
        (const __attribute__((address_space(1))) uint32_t*)g,
        (__attribute__((address_space(3))) uint32_t*)l,
        16, 0, 0);
}

#define WTV(n) asm volatile("s_waitcnt vmcnt(" #n ")" ::: "memory")

// ---- weights fp32 -> bf16, granule layout wsA[kb][m][8] ----
__global__ void repack_w(const float* __restrict__ w, unsigned short* __restrict__ wsA) {
    int idx = blockIdx.x * 256 + threadIdx.x;   // 0..81919, 4 k-elements each
    float4 v = ((const float4*)w)[idx];
    int m = idx / 320;                          // w is [256][1280] row-major
    int k = (idx - m * 320) << 2;
    ushort4v o = { f2bf(v.x), f2bf(v.y), f2bf(v.z), f2bf(v.w) };
    *(ushort4v*)(wsA + ((size_t)(k >> 3) << 11) + (m << 3) + (k & 7)) = o;
}

// ---- v0 (x), v1 (prefix max over h), v2 (suffix max over h) ----
// grid 1024 = (b:8, cb:32, wq:4); block 256.
// Strip [8c][128h][32w] fp32 staged in LDS once via global_load_lds (x read ONCE).
// Wave w0 DMAs its own channels {2w0, 2w0+1}; progressive counted vmcnt per h-chunk.
__global__ __launch_bounds__(256) void scan_h(const float* __restrict__ x,
                                              unsigned short* __restrict__ wsB) {
    int idx = blockIdx.x;
    int wq = idx & 3, cb = (idx >> 2) & 31, b = idx >> 7;
    int t = threadIdx.x;
    int w0 = t >> 6, lane = t & 63;
    int c = t >> 5, wi = t & 31;                  // scan mapping: column (c, wi)

    __shared__ float xs[8 * 128 * 32];            // [c][h][w], 128 KiB
    __shared__ unsigned short sm0[16 * 32 * 8];   // [hh][wi][c], 8 KB
    __shared__ unsigned short sm1[16 * 32 * 8];

    const float* xb = x + (((size_t)(b * 256 + cb * 8)) << 14) + wq * 32;

    // DMA: instr r -> channel cc = 2*w0+(r&1), h-rows [(r>>1)*8, +8).
    {
        int hh = lane >> 3, w4 = lane & 7;
#pragma unroll
        for (int r = 0; r < 32; ++r) {
            int cc = (w0 << 1) + (r & 1);
            int h0 = (r >> 1) << 3;
            const float* g = xb + ((size_t)cc << 14) + (size_t)(h0 + hh) * 128 + (w4 << 2);
            load_lds16(g, (char*)(xs + ((cc << 7) + h0) * 32) + lane * 16);
        }
    }

    unsigned short* d0 = wsB + (((size_t)(cb)      * N_) << 3);
    unsigned short* d1 = wsB + (((size_t)(32 + cb) * N_) << 3);
    unsigned short* d2 = wsB + (((size_t)(64 + cb) * N_) << 3);
    size_t nbase = ((size_t)b << 14) + wq * 32;

    // forward: v0 -> d0, prefix -> d1
    float r = -INFINITY;
#pragma unroll
    for (int hb = 0; hb < 8; ++hb) {
        // own wave's instrs for this chunk are the first 4*(hb+1)
        if      (hb == 0) WTV(28);
        else if (hb == 1) WTV(24);
        else if (hb == 2) WTV(20);
        else if (hb == 3) WTV(16);
        else if (hb == 4) WTV(12);
        else if (hb == 5) WTV(8);
        else if (hb == 6) WTV(4);
        else              WTV(0);
        __builtin_amdgcn_sched_barrier(0);
        int h0 = hb << 4;
#pragma unroll
        for (int hh = 0; hh < 16; ++hh) {
            float v = xs[((c << 7) + h0 + hh) * 32 + wi];
            r = fmaxf(r, v);
            sm0[(((hh << 5) + wi) << 3) + c] = f2bf(v);
            sm1[(((hh << 5) + wi) << 3) + c] = f2bf(r);
        }
        __syncthreads();
#pragma unroll
        for (int k = 0; k < 2; ++k) {
            int p = t + (k << 8);
            int hh = p >> 5, wo = p & 31;
            size_t n = nbase + (size_t)(h0 + hh) * 128 + wo;
            *(ushort8v*)(d0 + (n << 3)) = *(const ushort8v*)(sm0 + (((hh << 5) + wo) << 3));
            *(ushort8v*)(d1 + (n << 3)) = *(const ushort8v*)(sm1 + (((hh << 5) + wo) << 3));
        }
        __syncthreads();
    }

    // backward: suffix -> d2 (strip fully resident by now)
    r = -INFINITY;
#pragma unroll
    for (int hb = 7; hb >= 0; --hb) {
        int h0 = hb << 4;
#pragma unroll
        for (int hh = 15; hh >= 0; --hh) {
            float v = xs[((c << 7) + h0 + hh) * 32 + wi];
            r = fmaxf(r, v);
            sm0[(((hh << 5) + wi) << 3) + c] = f2bf(r);
        }
        __syncthreads();
#pragma unroll
        for (int k = 0; k < 2; ++k) {
            int p = t + (k << 8);
            int hh = p >> 5, wo = p & 31;
            size_t n = nbase + (size_t)(h0 + hh) * 128 + wo;
            *(ushort8v*)(d2 + (n << 3)) = *(const ushort8v*)(sm0 + (((hh << 5) + wo) << 3));
        }
        __syncthreads();
    }
}

// ---- v3 (prefix max over w), v4 (suffix max over w) ----
// grid 1024 = (b:8, cb:32, hq:4); block 256.
// Strip [row=c*32+h][128w] fp32 in LDS, granule-XOR swizzled (phys = g ^ (row&7))
// via pre-swizzled per-lane GLOBAL source (LDS dest linear). x read ONCE.
// Thread (c=t&7, h=t>>3) scans its own row; each wave DMAs exactly its own rows.
__global__ __launch_bounds__(256) void scan_w(const float* __restrict__ x,
                                              unsigned short* __restrict__ wsB) {
    int idx = blockIdx.x;
    int hq = idx & 3, cb = (idx >> 2) & 31, b = idx >> 7;
    int t = threadIdx.x;
    int w0 = t >> 6, lane = t & 63;
    int c = t & 7, h = t >> 3;                   // scan mapping: row rs = c*32 + h

    __shared__ float xs[256 * 128];              // [rs][w phys-swizzled], 128 KiB
    __shared__ unsigned short po[16 * 32 * 8];   // [w16][h32][c8], granule-XOR, 8 KB

    const float* xb = x + (((size_t)(b * 256 + cb * 8)) << 14) + ((size_t)(hq * 32) << 7);

    // DMA: wave w0 owns rows (cc, hl) hl in [8w0, 8w0+8). instr r: cc=r>>2, row-pair rs0.
    {
        int rsel = lane >> 5, gp = lane & 31;
#pragma unroll
        for (int r = 0; r < 32; ++r) {
            int cc  = r >> 2;
            int rs0 = (cc << 5) + (w0 << 3) + ((r & 3) << 1);
            int row = rs0 + rsel;
            int gl  = gp ^ (row & 7);            // inverse swizzle on global source
            const float* g = xb + ((size_t)cc << 14) + ((size_t)(row & 31) << 7) + (gl << 2);
            load_lds16(g, (char*)(xs + (rs0 << 7)) + lane * 16);
        }
    }
    WTV(0);                                      // own rows ready; no cross-wave dep
    __builtin_amdgcn_sched_barrier(0);

    unsigned short* d3 = wsB + (((size_t)(96  + cb) * N_) << 3);
    unsigned short* d4 = wsB + (((size_t)(128 + cb) * N_) << 3);
    size_t nrow0 = ((size_t)b << 14) + (size_t)(hq * 32) * 128;
    int rs = (c << 5) + h;
    int sw = rs & 7;

    // forward prefix -> d3
    {
        float rr = -INFINITY;
#pragma unroll
        for (int wc = 0; wc < 8; ++wc) {
#pragma unroll
            for (int g = 0; g < 4; ++g) {
                int l = (wc << 2) + g;
                float4v v = *(const float4v*)(xs + (rs << 7) + ((l ^ sw) << 2));
#pragma unroll
                for (int e = 0; e < 4; ++e) {
                    rr = fmaxf(rr, v[e]);
                    int wloc = (g << 2) + e;
                    int G = (wloc << 5) + h;
                    po[((G ^ (wloc & 7)) << 3) + c] = f2bf(rr);
                }
            }
            __syncthreads();
#pragma unroll
            for (int k = 0; k < 2; ++k) {
                int p = t + (k << 8);
                int ww = p & 15, hh = p >> 4;
                int G = (ww << 5) + hh;
                size_t n = nrow0 + (size_t)hh * 128 + (wc << 4) + ww;
                *(ushort8v*)(d3 + (n << 3)) = *(const ushort8v*)(po + ((G ^ (ww & 7)) << 3));
            }
            __syncthreads();
        }
    }
    // backward suffix -> d4
    {
        float rr = -INFINITY;
#pragma unroll
        for (int wc = 7; wc >= 0; --wc) {
#pragma unroll
            for (int g = 3; g >= 0; --g) {
                int l = (wc << 2) + g;
                float4v v = *(const float4v*)(xs + (rs << 7) + ((l ^ sw) << 2));
#pragma unroll
                for (int e = 3; e >= 0; --e) {
                    rr = fmaxf(rr, v[e]);
                    int wloc = (g << 2) + e;
                    int G = (wloc << 5) + h;
                    po[((G ^ (wloc & 7)) << 3) + c] = f2bf(rr);
                }
            }
            __syncthreads();
#pragma unroll
            for (int k = 0; k < 2; ++k) {
                int p = t + (k << 8);
                int ww = p & 15, hh = p >> 4;
                int G = (ww << 5) + hh;
                size_t n = nrow0 + (size_t)hh * 128 + (wc << 4) + ww;
                *(ushort8v*)(d4 + (n << 3)) = *(const ushort8v*)(po + ((G ^ (ww & 7)) << 3));
            }
            __syncthreads();
        }
    }
}

// ---- GEMM: C[256,131072] = A[256,1280] * B[1280,131072], bf16 MFMA ----
// 256x256 tile, BK=64, 8 waves (2M x 4N), double-buffered 128 KiB LDS,
// stage-ahead 1 tile with counted vmcnt(8), raw s_barrier (no vmcnt(0) drain in loop).

__device__ __forceinline__ void stage_tile(
    const unsigned short* __restrict__ wsA, const unsigned short* __restrict__ wsB,
    int t, int n0, unsigned short* As, unsigned short* Bs, int tid) {
    const unsigned short* ga = wsA + ((((size_t)t << 11) + tid) << 3);
#pragma unroll
    for (int r = 0; r < 4; ++r)
        load_lds16(ga + (r << 12), As + (((r << 9) + tid) << 3));
    int kb0 = t << 3;
#pragma unroll
    for (int r = 0; r < 4; ++r) {
        int idx = (r << 9) + tid;
        load_lds16(wsB + (((size_t)(kb0 + (idx >> 8)) * N_ + n0 + (idx & 255)) << 3),
                   Bs + ((size_t)idx << 3));
    }
}

__device__ __forceinline__ void compute_tile(
    const unsigned short* __restrict__ Ab, const unsigned short* __restrict__ Bb,
    int wr, int wc, int q, int lr, float4v (&acc)[8][4]) {
#pragma unroll
    for (int h = 0; h < 2; ++h) {
        short8v a[8], bb[4];
        int kq = (h << 2) + q;
#pragma unroll
        for (int mi = 0; mi < 8; ++mi)
            a[mi] = *(const short8v*)(Ab + (((kq << 8) + (wr << 7) + (mi << 4) + lr) << 3));
#pragma unroll
        for (int ni = 0; ni < 4; ++ni)
            bb[ni] = *(const short8v*)(Bb + (((kq << 8) + (wc << 6) + (ni << 4) + lr) << 3));
        __builtin_amdgcn_s_setprio(1);
#pragma unroll
        for (int mi = 0; mi < 8; ++mi)
#pragma unroll
            for (int ni = 0; ni < 4; ++ni)
                acc[mi][ni] = __builtin_amdgcn_mfma_f32_16x16x32_bf16(a[mi], bb[ni], acc[mi][ni], 0, 0, 0);
        __builtin_amdgcn_s_setprio(0);
    }
}

__global__ __launch_bounds__(512, 2) void gemm_k(
    const unsigned short* __restrict__ wsA, const unsigned short* __restrict__ wsB,
    const float* __restrict__ bias, float* __restrict__ out) {
    __shared__ __align__(16) unsigned short As[2][16384];
    __shared__ __align__(16) unsigned short Bs[2][16384];

    int tid  = threadIdx.x;
    int lane = tid & 63, wid = tid >> 6;
    int wr = wid >> 2, wc = wid & 3;
    int q  = lane >> 4, lr = lane & 15;
    int bid = blockIdx.x;
    int n0 = (((bid & 7) << 6) + (bid >> 3)) << 8;

    float4v acc[8][4];
#pragma unroll
    for (int mi = 0; mi < 8; ++mi)
#pragma unroll
        for (int ni = 0; ni < 4; ++ni)
            acc[mi][ni] = (float4v){0.f, 0.f, 0.f, 0.f};

    stage_tile(wsA, wsB, 0, n0, As[0], Bs[0], tid);
    stage_tile(wsA, wsB, 1, n0, As[1], Bs[1], tid);
    asm volatile("s_waitcnt vmcnt(8)" ::: "memory");
    __builtin_amdgcn_s_barrier();
    __builtin_amdgcn_sched_barrier(0);

#pragma unroll 1
    for (int t = 0; t < 18; t += 2) {
        compute_tile(As[0], Bs[0], wr, wc, q, lr, acc);
        __builtin_amdgcn_s_barrier();
        __builtin_amdgcn_sched_barrier(0);
        stage_tile(wsA, wsB, t + 2, n0, As[0], Bs[0], tid);
        __builtin_amdgcn_sched_barrier(0);
        asm volatile("s_waitcnt vmcnt(8)" ::: "memory");
        __builtin_amdgcn_s_barrier();
        __builtin_amdgcn_sched_barrier(0);

        compute_tile(As[1], Bs[1], wr, wc, q, lr, acc);
        __builtin_amdgcn_s_barrier();
        __builtin_amdgcn_sched_barrier(0);
        stage_tile(wsA, wsB, t + 3, n0, As[1], Bs[1], tid);
        __builtin_amdgcn_sched_barrier(0);
        asm volatile("s_waitcnt vmcnt(8)" ::: "memory");
        __builtin_amdgcn_s_barrier();
        __builtin_amdgcn_sched_barrier(0);
    }
    compute_tile(As[0], Bs[0], wr, wc, q, lr, acc);
    __builtin_amdgcn_s_barrier();
    asm volatile("s_waitcnt vmcnt(0)" ::: "memory");
    __builtin_amdgcn_s_barrier();
    __builtin_amdgcn_sched_barrier(0);
    compute_tile(As[1], Bs[1], wr, wc, q, lr, acc);

#pragma unroll
    for (int mi = 0; mi < 8; ++mi) {
        int rowb = (wr << 7) + (mi << 4) + (q << 2);
#pragma unroll
        for (int ni = 0; ni < 4; ++ni) {
            int col = n0 + (wc << 6) + (ni << 4) + lr;
            int b   = col >> 14, p = col & 16383;
            float* op = out + ((size_t)((b << 8) + rowb) << 14) + p;
#pragma unroll
            for (int r = 0; r < 4; ++r)
                op[(size_t)r << 14] = acc[mi][ni][r] + bias[rowb + r];
        }
    }
}

extern "C" void kernel_launch(void* const* d_in, const int* in_sizes, int n_in,
                              void* d_out, int out_size, void* d_ws, size_t ws_size,
                              hipStream_t stream) {
    const float* x  = (const float*)d_in[0];
    const float* cw = (const float*)d_in[1];
    const float* cb = (const float*)d_in[2];
    float* out = (float*)d_out;

    unsigned short* wsA = (unsigned short*)d_ws;
    unsigned short* wsB = wsA + 327680;

    repack_w<<<320, 256, 0, stream>>>(cw, wsA);
    scan_h<<<1024, 256, 0, stream>>>(x, wsB);
    scan_w<<<1024, 256, 0, stream>>>(x, wsB);
    gemm_k<<<dim3(512), 512, 0, stream>>>(wsA, wsB, cb, out);
}

// Round 4
// 427.304 us; speedup vs baseline: 1.2853x; 1.0284x over previous
//
#include <hip/hip_runtime.h>
#include <stdint.h>

// B=8, C=256, H=128, W=128. out = W[256,1280] @ concat(x,cummaxH,revcummaxH,cummaxW,revcummaxW) + bias
// GEMM: M=256, K=1280, N=131072 bf16 MFMA.
// ws: wsA [kb=160][m=256][j=8] bf16 weights (granule layout, k=kb*8+j);
//     wsB [kb=160][n=131072][j=8] bf16.

#define N_  131072
#define K_  1280

typedef unsigned short ushort8v __attribute__((ext_vector_type(8)));
typedef unsigned short ushort4v __attribute__((ext_vector_type(4)));
typedef short          short8v  __attribute__((ext_vector_type(8)));
typedef float          float4v  __attribute__((ext_vector_type(4)));
typedef unsigned int   uint2v   __attribute__((ext_vector_type(2)));
typedef unsigned int   uint4v   __attribute__((ext_vector_type(4)));

__device__ __forceinline__ unsigned short f2bf(float f) {
    unsigned int u = __builtin_bit_cast(unsigned int, f);
    u += 0x7fffu + ((u >> 16) & 1u);           // RNE
    return (unsigned short)(u >> 16);
}

__device__ __forceinline__ void load_lds16(const void* g, void* l) {
    __builtin_amdgcn_global_load_lds(
        (const __attribute__((address_space(1))) uint32_t*)g,
        (__attribute__((address_space(3))) uint32_t*)l,
        16, 0, 0);
}

#define WTV(n) asm volatile("s_waitcnt vmcnt(" #n ")" ::: "memory")
// lgkm-only barrier: does NOT drain global stores (unlike __syncthreads)
#define LGKM_BAR() do { \
    asm volatile("s_waitcnt lgkmcnt(0)" ::: "memory"); \
    __builtin_amdgcn_s_barrier(); \
    __builtin_amdgcn_sched_barrier(0); \
} while (0)

// ---- weights fp32 -> bf16, granule layout wsA[kb][m][8] ----
__global__ void repack_w(const float* __restrict__ w, unsigned short* __restrict__ wsA) {
    int idx = blockIdx.x * 256 + threadIdx.x;   // 0..81919, 4 k-elements each
    float4 v = ((const float4*)w)[idx];
    int m = idx / 320;                          // w is [256][1280] row-major
    int k = (idx - m * 320) << 2;
    ushort4v o = { f2bf(v.x), f2bf(v.y), f2bf(v.z), f2bf(v.w) };
    *(ushort4v*)(wsA + ((size_t)(k >> 3) << 11) + (m << 3) + (k & 7)) = o;
}

// ---- v0 (x), v1 (prefix max over h), v2 (suffix max over h) ----
// grid 1024 = (b:8, cb:32, wq:4); block 256 (j=t>>5 channel, wi=t&31).
// Direct coalesced global reads (no xs LDS). Register prefetch 16/chunk.
// sm double-buffered, lgkm-only barriers (global stores never drained in-loop).
// Backward pass re-reads x (block footprint 512 KiB -> L3-hot).
__global__ __launch_bounds__(256) void scan_h(const float* __restrict__ x,
                                              unsigned short* __restrict__ wsB) {
    int idx = blockIdx.x;
    int wq = idx & 3, cb = (idx >> 2) & 31, b = idx >> 7;
    int t = threadIdx.x;
    int j = t >> 5, wi = t & 31;
    const float* src = x + (((size_t)(b * 256 + cb * 8 + j)) << 14) + wq * 32 + wi;

    __shared__ unsigned short sm0[2][4096];   // [hh][wi][j] granules, 8 KB each
    __shared__ unsigned short sm1[2][4096];

    unsigned short* d0 = wsB + (((size_t)(cb)      * N_) << 3);
    unsigned short* d1 = wsB + (((size_t)(32 + cb) * N_) << 3);
    unsigned short* d2 = wsB + (((size_t)(64 + cb) * N_) << 3);
    size_t nbase = ((size_t)b << 14) + wq * 32;

    float v[16];
    // ---- forward: v0 -> d0, prefix -> d1 ----
    {
        float r = -INFINITY;
#pragma unroll
        for (int hh = 0; hh < 16; ++hh) v[hh] = src[(size_t)hh << 7];
#pragma unroll
        for (int hb = 0; hb < 8; ++hb) {
            int p = hb & 1;
            int h0 = hb << 4;
#pragma unroll
            for (int hh = 0; hh < 16; ++hh) {
                float vv = v[hh];
                r = fmaxf(r, vv);
                sm0[p][(((hh << 5) + wi) << 3) + j] = f2bf(vv);
                sm1[p][(((hh << 5) + wi) << 3) + j] = f2bf(r);
            }
            if (hb < 7) {           // prefetch next chunk before barrier
                int h0n = (hb + 1) << 4;
#pragma unroll
                for (int hh = 0; hh < 16; ++hh) v[hh] = src[(size_t)(h0n + hh) << 7];
            }
            LGKM_BAR();
#pragma unroll
            for (int k = 0; k < 2; ++k) {
                int pp = t + (k << 8);
                int hh = pp >> 5, wo = pp & 31;
                size_t n = nbase + (size_t)(h0 + hh) * 128 + wo;
                *(ushort8v*)(d0 + (n << 3)) = *(const ushort8v*)(&sm0[p][((hh << 5) + wo) << 3]);
                *(ushort8v*)(d1 + (n << 3)) = *(const ushort8v*)(&sm1[p][((hh << 5) + wo) << 3]);
            }
        }
    }
    LGKM_BAR();    // protect sm reuse between sweeps
    // ---- backward: suffix -> d2 ----
    {
        float r = -INFINITY;
#pragma unroll
        for (int hh = 0; hh < 16; ++hh) v[hh] = src[(size_t)(112 + hh) << 7];
#pragma unroll
        for (int hb = 7; hb >= 0; --hb) {
            int p = hb & 1;
            int h0 = hb << 4;
#pragma unroll
            for (int hh = 15; hh >= 0; --hh) {
                r = fmaxf(r, v[hh]);
                sm0[p][(((hh << 5) + wi) << 3) + j] = f2bf(r);
            }
            if (hb > 0) {
                int h0n = (hb - 1) << 4;
#pragma unroll
                for (int hh = 0; hh < 16; ++hh) v[hh] = src[(size_t)(h0n + hh) << 7];
            }
            LGKM_BAR();
#pragma unroll
            for (int k = 0; k < 2; ++k) {
                int pp = t + (k << 8);
                int hh = pp >> 5, wo = pp & 31;
                size_t n = nbase + (size_t)(h0 + hh) * 128 + wo;
                *(ushort8v*)(d2 + (n << 3)) = *(const ushort8v*)(&sm0[p][((hh << 5) + wo) << 3]);
            }
        }
    }
}

// ---- v3 (prefix max over w), v4 (suffix max over w) ----
// grid 1024 = (b:8, cb:32, hq:4); block 256 (c=t&7, h=t>>3 -> row rs=c*32+h).
// Strip staged ONCE as bf16 (RNE monotone => round-then-max == max-then-round),
// reg-staged with coalesced float4 reads, 16B-granule XOR phys = g ^ (rs&7).
// Both sweeps run from LDS. po double-buffered, lgkm-only barriers.
__global__ __launch_bounds__(256) void scan_w(const float* __restrict__ x,
                                              unsigned short* __restrict__ wsB) {
    int idx = blockIdx.x;
    int hq = idx & 3, cb = (idx >> 2) & 31, b = idx >> 7;
    int t = threadIdx.x;

    __shared__ unsigned short xs[256 * 128];   // [row][w] bf16, granule-XOR, 64 KB
    __shared__ unsigned short po[2][4096];     // [w16][h32][c8] granule-XOR, 8 KB each

    const float* xb = x + (((size_t)(b * 256 + cb * 8)) << 14) + ((size_t)(hq * 32) << 7);

    // reg-staging: 32 coalesced float4 per thread -> bf16 -> swizzled ds_write_b64
#pragma unroll
    for (int rr = 0; rr < 32; ++rr) {
        int f   = (rr << 8) + t;               // float4 id, row-major over strip
        int row = f >> 5, q = f & 31;          // row = c*32+hh, q = float4-in-row
        float4 vv = *(const float4*)(xb + ((size_t)(row >> 5) << 14) +
                                     ((row & 31) << 7) + (q << 2));
        uint2v u;
        u[0] = (unsigned int)f2bf(vv.x) | ((unsigned int)f2bf(vv.y) << 16);
        u[1] = (unsigned int)f2bf(vv.z) | ((unsigned int)f2bf(vv.w) << 16);
        int g = q >> 1, half = q & 1;
        int phys = g ^ (row & 7);
        *(uint2v*)((char*)xs + row * 256 + phys * 16 + half * 8) = u;
    }
    LGKM_BAR();

    unsigned short* d3 = wsB + (((size_t)(96  + cb) * N_) << 3);
    unsigned short* d4 = wsB + (((size_t)(128 + cb) * N_) << 3);
    size_t nrow0 = ((size_t)b << 14) + (size_t)(hq * 32) * 128;
    int c = t & 7, h = t >> 3;
    int rs = (c << 5) + h;
    int sw = rs & 7;
    int pb = 0;

    // ---- forward prefix -> d3 ----
    {
        float rr = -INFINITY;
#pragma unroll
        for (int wc = 0; wc < 8; ++wc) {
#pragma unroll
            for (int g2 = 0; g2 < 2; ++g2) {
                int g = (wc << 1) + g2;
                uint4v u = *(const uint4v*)((const char*)xs + rs * 256 + ((g ^ sw) << 4));
#pragma unroll
                for (int e = 0; e < 8; ++e) {
                    unsigned int w32 = u[e >> 1];
                    unsigned int bits = (e & 1) ? (w32 & 0xffff0000u) : (w32 << 16);
                    rr = fmaxf(rr, __builtin_bit_cast(float, bits));
                    int wloc = (g2 << 3) + e;
                    int G = (wloc << 5) + h;
                    po[pb][((G ^ (wloc & 7)) << 3) + c] =
                        (unsigned short)(__builtin_bit_cast(unsigned int, rr) >> 16);
                }
            }
            LGKM_BAR();
#pragma unroll
            for (int k = 0; k < 2; ++k) {
                int p = t + (k << 8);
                int ww = p & 15, hh = p >> 4;
                int G = (ww << 5) + hh;
                size_t n = nrow0 + (size_t)hh * 128 + (wc << 4) + ww;
                *(ushort8v*)(d3 + (n << 3)) = *(const ushort8v*)(&po[pb][(G ^ (ww & 7)) << 3]);
            }
            pb ^= 1;
        }
    }
    // ---- backward suffix -> d4 ----
    {
        float rr = -INFINITY;
#pragma unroll
        for (int wc = 7; wc >= 0; --wc) {
#pragma unroll
            for (int g2 = 1; g2 >= 0; --g2) {
                int g = (wc << 1) + g2;
                uint4v u = *(const uint4v*)((const char*)xs + rs * 256 + ((g ^ sw) << 4));
#pragma unroll
                for (int e = 7; e >= 0; --e) {
                    unsigned int w32 = u[e >> 1];
                    unsigned int bits = (e & 1) ? (w32 & 0xffff0000u) : (w32 << 16);
                    rr = fmaxf(rr, __builtin_bit_cast(float, bits));
                    int wloc = (g2 << 3) + e;
                    int G = (wloc << 5) + h;
                    po[pb][((G ^ (wloc & 7)) << 3) + c] =
                        (unsigned short)(__builtin_bit_cast(unsigned int, rr) >> 16);
                }
            }
            LGKM_BAR();
#pragma unroll
            for (int k = 0; k < 2; ++k) {
                int p = t + (k << 8);
                int ww = p & 15, hh = p >> 4;
                int G = (ww << 5) + hh;
                size_t n = nrow0 + (size_t)hh * 128 + (wc << 4) + ww;
                *(ushort8v*)(d4 + (n << 3)) = *(const ushort8v*)(&po[pb][(G ^ (ww & 7)) << 3]);
            }
            pb ^= 1;
        }
    }
}

// ---- GEMM: C[256,131072] = A[256,1280] * B[1280,131072], bf16 MFMA ----
// 256x256 tile, BK=64, 8 waves (2M x 4N), double-buffered 128 KiB LDS,
// stage-ahead 1 tile with counted vmcnt(8), raw s_barrier (no vmcnt(0) drain in loop).

__device__ __forceinline__ void stage_tile(
    const unsigned short* __restrict__ wsA, const unsigned short* __restrict__ wsB,
    int t, int n0, unsigned short* As, unsigned short* Bs, int tid) {
    const unsigned short* ga = wsA + ((((size_t)t << 11) + tid) << 3);
#pragma unroll
    for (int r = 0; r < 4; ++r)
        load_lds16(ga + (r << 12), As + (((r << 9) + tid) << 3));
    int kb0 = t << 3;
#pragma unroll
    for (int r = 0; r < 4; ++r) {
        int idx = (r << 9) + tid;
        load_lds16(wsB + (((size_t)(kb0 + (idx >> 8)) * N_ + n0 + (idx & 255)) << 3),
                   Bs + ((size_t)idx << 3));
    }
}

__device__ __forceinline__ void compute_tile(
    const unsigned short* __restrict__ Ab, const unsigned short* __restrict__ Bb,
    int wr, int wc, int q, int lr, float4v (&acc)[8][4]) {
#pragma unroll
    for (int h = 0; h < 2; ++h) {
        short8v a[8], bb[4];
        int kq = (h << 2) + q;
#pragma unroll
        for (int mi = 0; mi < 8; ++mi)
            a[mi] = *(const short8v*)(Ab + (((kq << 8) + (wr << 7) + (mi << 4) + lr) << 3));
#pragma unroll
        for (int ni = 0; ni < 4; ++ni)
            bb[ni] = *(const short8v*)(Bb + (((kq << 8) + (wc << 6) + (ni << 4) + lr) << 3));
        __builtin_amdgcn_s_setprio(1);
#pragma unroll
        for (int mi = 0; mi < 8; ++mi)
#pragma unroll
            for (int ni = 0; ni < 4; ++ni)
                acc[mi][ni] = __builtin_amdgcn_mfma_f32_16x16x32_bf16(a[mi], bb[ni], acc[mi][ni], 0, 0, 0);
        __builtin_amdgcn_s_setprio(0);
    }
}

__global__ __launch_bounds__(512, 2) void gemm_k(
    const unsigned short* __restrict__ wsA, const unsigned short* __restrict__ wsB,
    const float* __restrict__ bias, float* __restrict__ out) {
    __shared__ __align__(16) unsigned short As[2][16384];
    __shared__ __align__(16) unsigned short Bs[2][16384];

    int tid  = threadIdx.x;
    int lane = tid & 63, wid = tid >> 6;
    int wr = wid >> 2, wc = wid & 3;
    int q  = lane >> 4, lr = lane & 15;
    int bid = blockIdx.x;
    int n0 = (((bid & 7) << 6) + (bid >> 3)) << 8;

    float4v acc[8][4];
#pragma unroll
    for (int mi = 0; mi < 8; ++mi)
#pragma unroll
        for (int ni = 0; ni < 4; ++ni)
            acc[mi][ni] = (float4v){0.f, 0.f, 0.f, 0.f};

    stage_tile(wsA, wsB, 0, n0, As[0], Bs[0], tid);
    stage_tile(wsA, wsB, 1, n0, As[1], Bs[1], tid);
    asm volatile("s_waitcnt vmcnt(8)" ::: "memory");
    __builtin_amdgcn_s_barrier();
    __builtin_amdgcn_sched_barrier(0);

#pragma unroll 1
    for (int t = 0; t < 18; t += 2) {
        compute_tile(As[0], Bs[0], wr, wc, q, lr, acc);
        __builtin_amdgcn_s_barrier();
        __builtin_amdgcn_sched_barrier(0);
        stage_tile(wsA, wsB, t + 2, n0, As[0], Bs[0], tid);
        __builtin_amdgcn_sched_barrier(0);
        asm volatile("s_waitcnt vmcnt(8)" ::: "memory");
        __builtin_amdgcn_s_barrier();
        __builtin_amdgcn_sched_barrier(0);

        compute_tile(As[1], Bs[1], wr, wc, q, lr, acc);
        __builtin_amdgcn_s_barrier();
        __builtin_amdgcn_sched_barrier(0);
        stage_tile(wsA, wsB, t + 3, n0, As[1], Bs[1], tid);
        __builtin_amdgcn_sched_barrier(0);
        asm volatile("s_waitcnt vmcnt(8)" ::: "memory");
        __builtin_amdgcn_s_barrier();
        __builtin_amdgcn_sched_barrier(0);
    }
    compute_tile(As[0], Bs[0], wr, wc, q, lr, acc);
    __builtin_amdgcn_s_barrier();
    asm volatile("s_waitcnt vmcnt(0)" ::: "memory");
    __builtin_amdgcn_s_barrier();
    __builtin_amdgcn_sched_barrier(0);
    compute_tile(As[1], Bs[1], wr, wc, q, lr, acc);

#pragma unroll
    for (int mi = 0; mi < 8; ++mi) {
        int rowb = (wr << 7) + (mi << 4) + (q << 2);
#pragma unroll
        for (int ni = 0; ni < 4; ++ni) {
            int col = n0 + (wc << 6) + (ni << 4) + lr;
            int b   = col >> 14, p = col & 16383;
            float* op = out + ((size_t)((b << 8) + rowb) << 14) + p;
#pragma unroll
            for (int r = 0; r < 4; ++r)
                op[(size_t)r << 14] = acc[mi][ni][r] + bias[rowb + r];
        }
    }
}

extern "C" void kernel_launch(void* const* d_in, const int* in_sizes, int n_in,
                              void* d_out, int out_size, void* d_ws, size_t ws_size,
                              hipStream_t stream) {
    const float* x  = (const float*)d_in[0];
    const float* cw = (const float*)d_in[1];
    const float* cb = (const float*)d_in[2];
    float* out = (float*)d_out;

    unsigned short* wsA = (unsigned short*)d_ws;
    unsigned short* wsB = wsA + 327680;

    repack_w<<<320, 256, 0, stream>>>(cw, wsA);
    scan_h<<<1024, 256, 0, stream>>>(x, wsB);
    scan_w<<<1024, 256, 0, stream>>>(x, wsB);
    gemm_k<<<dim3(512), 512, 0, stream>>>(wsA, wsB, cb, out);
}